// Round 1
// baseline (321.922 us; speedup 1.0000x reference)
//
#include <hip/hip_runtime.h>
#include <math.h>

typedef unsigned short ushort_t;
typedef __attribute__((ext_vector_type(8))) short short8;
typedef __attribute__((ext_vector_type(4))) float f32x4;

#define B_  16
#define HW_ 1024
#define C_  64
#define NC_ 5
#define D1_ 96
#define NH_ 4
#define DH_ 64

__device__ __forceinline__ ushort_t f2bf(float f) {
    unsigned u = __float_as_uint(f);
    u = u + 0x7fffu + ((u >> 16) & 1u);   // round-to-nearest-even
    return (ushort_t)(u >> 16);
}

// ---------------- K1: logits = xt @ wb_w + wb_b ; weight1 = softmax over classes ----------------
__global__ __launch_bounds__(256) void k1_logits(const float* __restrict__ x,
                                                 const float* __restrict__ wb_w,
                                                 const float* __restrict__ wb_b,
                                                 float* __restrict__ logitsT,
                                                 float* __restrict__ w1) {
    __shared__ float sw[C_ * NC_];
    int t = threadIdx.x;
    for (int i = t; i < C_ * NC_; i += 256) sw[i] = wb_w[i];
    __syncthreads();
    int idx = blockIdx.x * 256 + t;             // 0..16383
    int b = idx >> 10, hw = idx & 1023;
    const float* xb = x + (size_t)b * C_ * HW_;
    float acc[NC_];
#pragma unroll
    for (int j = 0; j < NC_; j++) acc[j] = wb_b[j];
    for (int c = 0; c < C_; c++) {
        float xv = xb[c * HW_ + hw];
#pragma unroll
        for (int j = 0; j < NC_; j++) acc[j] += xv * sw[c * NC_ + j];
    }
    float m = acc[0];
#pragma unroll
    for (int j = 1; j < NC_; j++) m = fmaxf(m, acc[j]);
    float e[NC_], s = 0.f;
#pragma unroll
    for (int j = 0; j < NC_; j++) { e[j] = __expf(acc[j] - m); s += e[j]; }
    float inv = 1.f / s;
#pragma unroll
    for (int j = 0; j < NC_; j++) {
        logitsT[((size_t)b * NC_ + j) * HW_ + hw] = acc[j];
        w1[(size_t)idx * NC_ + j] = e[j] * inv;
    }
}

// ---------------- K2: weight2 = softmax over HW; class_feat1 = weight2 @ xt ----------------
__global__ __launch_bounds__(256) void k2_pool(const float* __restrict__ x,
                                               const float* __restrict__ logitsT,
                                               float* __restrict__ cf1) {
    __shared__ float p[HW_];
    __shared__ float red[256];
    int t = threadIdx.x;
    int b = blockIdx.x / NC_, c = blockIdx.x % NC_;
    const float* lp = logitsT + ((size_t)b * NC_ + c) * HW_;
    float lm = -1e30f;
    for (int i = t; i < HW_; i += 256) lm = fmaxf(lm, lp[i]);
    red[t] = lm; __syncthreads();
    for (int s2 = 128; s2 > 0; s2 >>= 1) { if (t < s2) red[t] = fmaxf(red[t], red[t + s2]); __syncthreads(); }
    float m = red[0];
    __syncthreads();
    float ls = 0.f;
    for (int i = t; i < HW_; i += 256) { float e = __expf(lp[i] - m); p[i] = e; ls += e; }
    red[t] = ls; __syncthreads();
    for (int s2 = 128; s2 > 0; s2 >>= 1) { if (t < s2) red[t] += red[t + s2]; __syncthreads(); }
    float inv = 1.f / red[0];
    int ch = t & 63, g = t >> 6;
    const float* xb = x + ((size_t)b * C_ + ch) * HW_;
    float acc = 0.f;
    for (int i = 0; i < 256; i++) { int hw = g * 256 + i; acc += p[hw] * xb[hw]; }
    __syncthreads();
    red[t] = acc; __syncthreads();
    if (g == 0) {
        float a = red[t] + red[t + 64] + red[t + 128] + red[t + 192];
        cf1[((size_t)b * NC_ + c) * C_ + ch] = a * inv;
    }
}

// ---------------- K_kv: kh = memory@wk+bk [5,96]; vh = memory@wv+bv [5,64] ----------------
__global__ __launch_bounds__(256) void k_kv(const float* __restrict__ mem,
                                            const float* __restrict__ wk, const float* __restrict__ bk,
                                            const float* __restrict__ wv, const float* __restrict__ bv,
                                            float* __restrict__ kh, float* __restrict__ vh) {
    __shared__ float sm[NC_ * D1_];
    int t = threadIdx.x;
    for (int i = t; i < NC_ * D1_; i += 256) sm[i] = mem[i];
    __syncthreads();
    for (int idx = t; idx < NC_ * D1_; idx += 256) {
        int i = idx / D1_, k = idx % D1_;
        float a = bk[k];
        for (int d = 0; d < D1_; d++) a += sm[i * D1_ + d] * wk[d * D1_ + k];
        kh[idx] = a;
    }
    for (int idx = t; idx < NC_ * DH_; idx += 256) {
        int i = idx / DH_, dv = idx % DH_;
        float a = bv[dv];
        for (int d = 0; d < D1_; d++) a += sm[i * D1_ + d] * wv[d * DH_ + dv];
        vh[idx] = a;
    }
}

// ---------------- K3: MHA1 (n_head=1, dk=96, dv=64) + residual + LN, per batch ----------------
__global__ __launch_bounds__(256) void k3_mha1(const float* __restrict__ cf1,
                                               const float* __restrict__ wq, const float* __restrict__ bq,
                                               const float* __restrict__ kh, const float* __restrict__ vh,
                                               const float* __restrict__ fc, const float* __restrict__ fcb,
                                               const float* __restrict__ lng, const float* __restrict__ lnb,
                                               float* __restrict__ cfs) {
    __shared__ float cs[NC_ * C_];
    __shared__ float q[NC_ * D1_];
    __shared__ float sc[NC_ * NC_];
    __shared__ float pp[NC_ * NC_];
    __shared__ float o[NC_ * C_];
    __shared__ float z[NC_ * C_];
    __shared__ float mu[NC_], rs[NC_];
    int t = threadIdx.x, b = blockIdx.x;
    for (int i = t; i < NC_ * C_; i += 256) cs[i] = cf1[(size_t)b * NC_ * C_ + i];
    __syncthreads();
    for (int idx = t; idx < NC_ * D1_; idx += 256) {
        int i = idx / D1_, k = idx % D1_;
        float a = bq[k];
        for (int c = 0; c < C_; c++) a += cs[i * C_ + c] * wq[c * D1_ + k];
        q[idx] = a;
    }
    __syncthreads();
    if (t < NC_ * NC_) {
        int i = t / NC_, j = t % NC_;
        float a = 0.f;
        for (int k = 0; k < D1_; k++) a += q[i * D1_ + k] * kh[j * D1_ + k];
        sc[t] = a * 0.1020620726159657f;     // 1/sqrt(96)
    }
    __syncthreads();
    if (t < NC_) {
        float m = sc[t * NC_];
        for (int j = 1; j < NC_; j++) m = fmaxf(m, sc[t * NC_ + j]);
        float e[NC_], s = 0.f;
        for (int j = 0; j < NC_; j++) { e[j] = __expf(sc[t * NC_ + j] - m); s += e[j]; }
        float inv = 1.f / s;
        for (int j = 0; j < NC_; j++) pp[t * NC_ + j] = e[j] * inv;
    }
    __syncthreads();
    for (int idx = t; idx < NC_ * C_; idx += 256) {
        int i = idx / C_, dv = idx % C_;
        float a = 0.f;
        for (int j = 0; j < NC_; j++) a += pp[i * NC_ + j] * vh[j * C_ + dv];
        o[idx] = a;
    }
    __syncthreads();
    for (int idx = t; idx < NC_ * C_; idx += 256) {
        int i = idx / C_, dd = idx % C_;
        float a = fcb[dd] + cs[idx];
        for (int c2 = 0; c2 < C_; c2++) a += o[i * C_ + c2] * fc[c2 * C_ + dd];
        z[idx] = a;
    }
    __syncthreads();
    if (t < NC_) {
        float s = 0.f;
        for (int d = 0; d < C_; d++) s += z[t * C_ + d];
        float mm = s / C_;
        float v = 0.f;
        for (int d = 0; d < C_; d++) { float dd2 = z[t * C_ + d] - mm; v += dd2 * dd2; }
        mu[t] = mm; rs[t] = rsqrtf(v / C_ + 1e-6f);
    }
    __syncthreads();
    for (int idx = t; idx < NC_ * C_; idx += 256) {
        int i = idx / C_, dd = idx % C_;
        cfs[(size_t)b * NC_ * C_ + idx] = (z[idx] - mu[i]) * rs[i] * lng[dd] + lnb[dd];
    }
}

// ---------------- K4: cf[b,hw,:] = sum_c weight1[b,hw,c] * cfs[b,c,:] ----------------
__global__ __launch_bounds__(256) void k4_redist(const float* __restrict__ w1,
                                                 const float* __restrict__ cfs,
                                                 float* __restrict__ cf) {
    int e = blockIdx.x * 256 + threadIdx.x;     // < 1048576
    int ch = e & 63, r = (e >> 6) & 1023, b = e >> 16;
    const float* wp = w1 + ((size_t)b * HW_ + r) * NC_;
    const float* cp = cfs + (size_t)b * NC_ * C_;
    float a = 0.f;
#pragma unroll
    for (int c2 = 0; c2 < NC_; c2++) a += wp[c2] * cp[c2 * C_ + ch];
    cf[e] = a;
}

// ---------------- K5: QKV projections -> bf16, [b,h,l,64] for Q,K; [b,h,l,64] for V (pre-transpose) ----
__global__ __launch_bounds__(256) void k5_proj(const float* __restrict__ cf,
                                               const float* __restrict__ wq, const float* __restrict__ bq,
                                               const float* __restrict__ wk, const float* __restrict__ bk,
                                               const float* __restrict__ wv, const float* __restrict__ bv,
                                               ushort_t* __restrict__ Qb, ushort_t* __restrict__ Kb,
                                               ushort_t* __restrict__ Vb) {
    __shared__ float rows[8][64];
    int t = threadIdx.x;
    int which = blockIdx.y;
    int m0 = blockIdx.x * 8;
    for (int e = t; e < 8 * 64; e += 256) rows[e >> 6][e & 63] = cf[(size_t)m0 * 64 + e];
    __syncthreads();
    const float* W = (which == 0) ? wq : (which == 1) ? wk : wv;
    const float* bias = (which == 0) ? bq : (which == 1) ? bk : bv;
    ushort_t* dst = (which == 0) ? Qb : (which == 1) ? Kb : Vb;
    int c = t;
    float bb = bias[c];
    float acc[8];
#pragma unroll
    for (int r = 0; r < 8; r++) acc[r] = bb;
    for (int k = 0; k < 64; k++) {
        float wv_ = W[k * 256 + c];
#pragma unroll
        for (int r = 0; r < 8; r++) acc[r] += rows[r][k] * wv_;
    }
    int h = c >> 6, dd = c & 63;
#pragma unroll
    for (int r = 0; r < 8; r++) {
        int m = m0 + r, b = m >> 10, hw = m & 1023;
        dst[(((size_t)(b * NH_ + h) * HW_) + hw) * DH_ + dd] = f2bf(acc[r]);
    }
}

// ---------------- KT: Vt[b,h,d,l] = Vb[b,h,l,d] ----------------
__global__ __launch_bounds__(256) void kt_transpose(const ushort_t* __restrict__ Vb,
                                                    ushort_t* __restrict__ Vt) {
    __shared__ ushort_t tile[64][65];
    int t = threadIdx.x;
    int bh = blockIdx.y;
    int l0 = blockIdx.x * 64;
    const ushort_t* src = Vb + (size_t)bh * HW_ * DH_ + (size_t)l0 * DH_;
    for (int e = t; e < 4096; e += 256) { int l = e >> 6, d = e & 63; tile[d][l] = src[l * 64 + d]; }
    __syncthreads();
    ushort_t* dst = Vt + (size_t)bh * DH_ * HW_ + l0;
    for (int e = t; e < 4096; e += 256) { int d = e >> 6, l = e & 63; dst[(size_t)d * HW_ + l] = tile[d][l]; }
}

// ---------------- K6: MFMA bf16 flash attention (4 heads, L=1024, d=64) ----------------
// wave-per-16-q-rows; 32 keys/iter; S via 4 MFMAs (K-frags straight from global),
// online softmax via shfl width-16; P transposed C/D->A layout through per-wave LDS;
// PV via 4 MFMAs against Vt (B^T-layout 16B loads).
__global__ __launch_bounds__(256) void k6_attn(const ushort_t* __restrict__ Qb,
                                               const ushort_t* __restrict__ Kb,
                                               const ushort_t* __restrict__ Vt,
                                               float* __restrict__ ao) {
    __shared__ float Pl[4][16 * 32];
    int t = threadIdx.x;
    int w = t >> 6;
    int lane = t & 63;
    int l15 = lane & 15;
    int quad = lane >> 4;
    int qt = blockIdx.x, h = blockIdx.y, b = blockIdx.z;
    int bh = b * NH_ + h;
    const ushort_t* Qp = Qb + (size_t)bh * HW_ * DH_;
    const ushort_t* Kp = Kb + (size_t)bh * HW_ * DH_;
    const ushort_t* Vp = Vt + (size_t)bh * DH_ * HW_;
    int row0 = qt * 64 + w * 16;
    int qrow = row0 + l15;
    short8 q0 = *(const short8*)(Qp + (size_t)qrow * DH_ + quad * 8);
    short8 q1 = *(const short8*)(Qp + (size_t)qrow * DH_ + 32 + quad * 8);
    f32x4 o0 = {0,0,0,0}, o1 = {0,0,0,0}, o2 = {0,0,0,0}, o3 = {0,0,0,0};
    float m4[4] = {-1e30f, -1e30f, -1e30f, -1e30f};
    float l4[4] = {0.f, 0.f, 0.f, 0.f};
    float* Pw = Pl[w];
    for (int kt = 0; kt < HW_ / 32; kt++) {
        int kbase = kt * 32;
        const ushort_t* K0 = Kp + (size_t)(kbase + l15) * DH_ + quad * 8;
        const ushort_t* K1 = Kp + (size_t)(kbase + 16 + l15) * DH_ + quad * 8;
        short8 ka0 = *(const short8*)(K0);
        short8 ka1 = *(const short8*)(K0 + 32);
        short8 kb0 = *(const short8*)(K1);
        short8 kb1 = *(const short8*)(K1 + 32);
        f32x4 z = {0,0,0,0};
        f32x4 s0 = __builtin_amdgcn_mfma_f32_16x16x32_bf16(q0, ka0, z, 0, 0, 0);
        s0 = __builtin_amdgcn_mfma_f32_16x16x32_bf16(q1, ka1, s0, 0, 0, 0);
        f32x4 s1 = __builtin_amdgcn_mfma_f32_16x16x32_bf16(q0, kb0, z, 0, 0, 0);
        s1 = __builtin_amdgcn_mfma_f32_16x16x32_bf16(q1, kb1, s1, 0, 0, 0);
        float p0[4], p1[4], alpha[4];
#pragma unroll
        for (int r = 0; r < 4; r++) {
            float sa = s0[r] * 0.125f, sb = s1[r] * 0.125f;
            float lm = fmaxf(sa, sb);
#pragma unroll
            for (int off = 1; off < 16; off <<= 1) lm = fmaxf(lm, __shfl_xor(lm, off, 16));
            float nm = fmaxf(m4[r], lm);
            alpha[r] = __expf(m4[r] - nm);
            p0[r] = __expf(sa - nm);
            p1[r] = __expf(sb - nm);
            float rsum = p0[r] + p1[r];
#pragma unroll
            for (int off = 1; off < 16; off <<= 1) rsum += __shfl_xor(rsum, off, 16);
            l4[r] = l4[r] * alpha[r] + rsum;
            m4[r] = nm;
        }
#pragma unroll
        for (int r = 0; r < 4; r++) {
            o0[r] *= alpha[r]; o1[r] *= alpha[r]; o2[r] *= alpha[r]; o3[r] *= alpha[r];
        }
        // P: C/D layout (row=quad*4+r, col=l15 / 16+l15) -> LDS [row][key]
#pragma unroll
        for (int r = 0; r < 4; r++) {
            Pw[(quad * 4 + r) * 32 + l15] = p0[r];
            Pw[(quad * 4 + r) * 32 + 16 + l15] = p1[r];
        }
        // read back in A layout: lane holds P[m=l15][k=quad*8+j]
        float4 pa = *(const float4*)(Pw + l15 * 32 + quad * 8);
        float4 pb = *(const float4*)(Pw + l15 * 32 + quad * 8 + 4);
        short8 pf;
        pf[0] = (short)f2bf(pa.x); pf[1] = (short)f2bf(pa.y);
        pf[2] = (short)f2bf(pa.z); pf[3] = (short)f2bf(pa.w);
        pf[4] = (short)f2bf(pb.x); pf[5] = (short)f2bf(pb.y);
        pf[6] = (short)f2bf(pb.z); pf[7] = (short)f2bf(pb.w);
        short8 v0 = *(const short8*)(Vp + (size_t)(0 * 16 + l15) * HW_ + kbase + quad * 8);
        short8 v1 = *(const short8*)(Vp + (size_t)(1 * 16 + l15) * HW_ + kbase + quad * 8);
        short8 v2 = *(const short8*)(Vp + (size_t)(2 * 16 + l15) * HW_ + kbase + quad * 8);
        short8 v3 = *(const short8*)(Vp + (size_t)(3 * 16 + l15) * HW_ + kbase + quad * 8);
        o0 = __builtin_amdgcn_mfma_f32_16x16x32_bf16(pf, v0, o0, 0, 0, 0);
        o1 = __builtin_amdgcn_mfma_f32_16x16x32_bf16(pf, v1, o1, 0, 0, 0);
        o2 = __builtin_amdgcn_mfma_f32_16x16x32_bf16(pf, v2, o2, 0, 0, 0);
        o3 = __builtin_amdgcn_mfma_f32_16x16x32_bf16(pf, v3, o3, 0, 0, 0);
    }
#pragma unroll
    for (int r = 0; r < 4; r++) {
        float inv = 1.f / l4[r];
        int rowg = row0 + quad * 4 + r;
        float* aop = ao + ((size_t)(b * HW_ + rowg)) * (NH_ * DH_) + h * DH_;
        aop[0 * 16 + l15] = o0[r] * inv;
        aop[1 * 16 + l15] = o1[r] * inv;
        aop[2 * 16 + l15] = o2[r] * inv;
        aop[3 * 16 + l15] = o3[r] * inv;
    }
}

// ---------------- K7: out = LN(ao @ fc + fcb + cf) -> transposed [b,64,32,32] ----------------
__global__ __launch_bounds__(256) void k7_final(const float* __restrict__ ao,
                                                const float* __restrict__ fc, const float* __restrict__ fcb,
                                                const float* __restrict__ cf,
                                                const float* __restrict__ lng, const float* __restrict__ lnb,
                                                float* __restrict__ out) {
    __shared__ float srow[4 * 256];
    __shared__ float T[64 * 4];
    int t = threadIdx.x, w = t >> 6, d = t & 63;
    int m0 = blockIdx.x * 4;
    int m = m0 + w;
    for (int e = t; e < 4 * 256; e += 256) srow[e] = ao[(size_t)m0 * 256 + e];
    __syncthreads();
    float a = fcb[d] + cf[(size_t)m * 64 + d];
    const float* s = srow + w * 256;
    for (int k = 0; k < 256; k++) a += s[k] * fc[k * 64 + d];
    float s1 = a, s2 = a * a;
#pragma unroll
    for (int off = 1; off < 64; off <<= 1) {
        s1 += __shfl_xor(s1, off, 64);
        s2 += __shfl_xor(s2, off, 64);
    }
    float mu = s1 * (1.f / 64.f);
    float var = s2 * (1.f / 64.f) - mu * mu;
    float rstd = rsqrtf(var + 1e-6f);
    float val = (a - mu) * rstd * lng[d] + lnb[d];
    T[d * 4 + w] = val;
    __syncthreads();
    if (t < 64) {
        int b = m0 >> 10, hw0 = m0 & 1023;
        float4 v = *(const float4*)&T[t * 4];
        *(float4*)&out[((size_t)b * 64 + t) * 1024 + hw0] = v;
    }
}

// ---------------- launcher ----------------
// workspace: ~52.7 MB used
extern "C" void kernel_launch(void* const* d_in, const int* in_sizes, int n_in,
                              void* d_out, int out_size, void* d_ws, size_t ws_size,
                              hipStream_t stream) {
    const float* x      = (const float*)d_in[0];
    const float* memory = (const float*)d_in[1];
    const float* wb_w   = (const float*)d_in[2];
    const float* wb_b   = (const float*)d_in[3];
    const float* a1_wq  = (const float*)d_in[4];
    const float* a1_bq  = (const float*)d_in[5];
    const float* a1_wk  = (const float*)d_in[6];
    const float* a1_bk  = (const float*)d_in[7];
    const float* a1_wv  = (const float*)d_in[8];
    const float* a1_bv  = (const float*)d_in[9];
    const float* a1_fc  = (const float*)d_in[10];
    const float* a1_fcb = (const float*)d_in[11];
    const float* a1_ln_g = (const float*)d_in[12];
    const float* a1_ln_b = (const float*)d_in[13];
    const float* a2_wq  = (const float*)d_in[14];
    const float* a2_bq  = (const float*)d_in[15];
    const float* a2_wk  = (const float*)d_in[16];
    const float* a2_bk  = (const float*)d_in[17];
    const float* a2_wv  = (const float*)d_in[18];
    const float* a2_bv  = (const float*)d_in[19];
    const float* a2_fc  = (const float*)d_in[20];
    const float* a2_fcb = (const float*)d_in[21];
    const float* a2_ln_g = (const float*)d_in[22];
    const float* a2_ln_b = (const float*)d_in[23];

    float* ws = (float*)d_ws;
    float* logitsT = ws;                                   // 16*5*1024
    float* w1  = logitsT + 16 * 5 * 1024;                  // 16*1024*5
    float* cf1 = w1 + 16 * 1024 * 5;                       // 16*5*64
    float* kh1 = cf1 + 16 * 5 * 64;                        // 5*96
    float* vh1 = kh1 + 5 * 96;                             // 5*64
    float* cfs = vh1 + 5 * 64;                             // 16*5*64
    float* cf  = cfs + 16 * 5 * 64;                        // 16*1024*64
    float* ao  = cf + 16 * 1024 * 64;                      // 16*1024*256
    ushort_t* Qb = (ushort_t*)(ao + 16 * 1024 * 256);      // 16*4*1024*64 bf16
    ushort_t* Kb = Qb + 16 * 4 * 1024 * 64;
    ushort_t* Vb = Kb + 16 * 4 * 1024 * 64;
    ushort_t* Vt = Vb + 16 * 4 * 1024 * 64;

    k1_logits<<<64, 256, 0, stream>>>(x, wb_w, wb_b, logitsT, w1);
    k2_pool<<<80, 256, 0, stream>>>(x, logitsT, cf1);
    k_kv<<<1, 256, 0, stream>>>(memory, a1_wk, a1_bk, a1_wv, a1_bv, kh1, vh1);
    k3_mha1<<<16, 256, 0, stream>>>(cf1, a1_wq, a1_bq, kh1, vh1, a1_fc, a1_fcb,
                                    a1_ln_g, a1_ln_b, cfs);
    k4_redist<<<4096, 256, 0, stream>>>(w1, cfs, cf);
    k5_proj<<<dim3(2048, 3), 256, 0, stream>>>(cf, a2_wq, a2_bq, a2_wk, a2_bk,
                                               a2_wv, a2_bv, Qb, Kb, Vb);
    kt_transpose<<<dim3(16, 64), 256, 0, stream>>>(Vb, Vt);
    k6_attn<<<dim3(16, 4, 16), 256, 0, stream>>>(Qb, Kb, Vt, ao);
    k7_final<<<4096, 256, 0, stream>>>(ao, a2_fc, a2_fcb, cf, a2_ln_g, a2_ln_b,
                                       (float*)d_out);
}